// Round 2
// baseline (175.275 us; speedup 1.0000x reference)
//
#include <hip/hip_runtime.h>

// Problem constants (fixed by the reference): B=8, H=320, W=1024, CH=CW=3, MAXINS=200
#define BATCH   8
#define HW      (320 * 1024)        // 327680 pixels per batch
#define ELEMS   (HW * 9)            // 2949120 floats per batch (divisible by 4)
#define MAXINS  200
#define BINS    (MAXINS * 9)        // 1800 floats = 7.2 KB

// ---------------------------------------------------------------------------
// Compress: per-block private LDS histogram -> plain stores of the partial
// into d_ws (no global atomics; the old atomic flush serialized 128-way
// same-address device-scope RMWs and cost ~100us).
// ---------------------------------------------------------------------------
__global__ __launch_bounds__(256) void epp_compress(
    const int* __restrict__ inst, const float* __restrict__ src,
    float* __restrict__ part, int nxblk)
{
    __shared__ float bins[BINS];
    const int b = blockIdx.y;

    for (int i = threadIdx.x; i < BINS; i += 256) bins[i] = 0.0f;
    __syncthreads();

    const int total4 = ELEMS / 4;                      // 737280 float4 per batch
    const int* __restrict__ instb = inst + b * HW;
    const float4* __restrict__ srcb = (const float4*)(src + (size_t)b * ELEMS);
    const int stride = nxblk * 256;

    // 2x manual unroll: both float4 loads + all id loads issue before the
    // LDS atomics, doubling memory-level parallelism per wave.
    for (int e4 = blockIdx.x * 256 + threadIdx.x; e4 < total4; e4 += 2 * stride) {
        const int e4b = e4 + stride;
        const bool hasb = (e4b < total4);

        float4 va = srcb[e4];
        float4 vb = hasb ? srcb[e4b] : make_float4(0.f, 0.f, 0.f, 0.f);

        const int ea = e4 * 4;
        const int eb = e4b * 4;
        float valsa[4] = {va.x, va.y, va.z, va.w};
        float valsb[4] = {vb.x, vb.y, vb.z, vb.w};
        int ida[4], idb[4];
#pragma unroll
        for (int k = 0; k < 4; ++k) {
            ida[k] = instb[(ea + k) / 9];
            idb[k] = hasb ? instb[(eb + k) / 9] : 0;
        }
#pragma unroll
        for (int k = 0; k < 4; ++k) {
            int ee = ea + k;
            int j  = ee - (ee / 9) * 9;
            atomicAdd(&bins[ida[k] * 9 + j], valsa[k] * 1.1f);
        }
        if (hasb) {
#pragma unroll
            for (int k = 0; k < 4; ++k) {
                int ee = eb + k;
                int j  = ee - (ee / 9) * 9;
                atomicAdd(&bins[idb[k] * 9 + j], valsb[k] * 1.1f);
            }
        }
    }
    __syncthreads();

    // Plain coalesced store of this block's partial histogram.
    float* __restrict__ pb = part + ((size_t)b * nxblk + blockIdx.x) * BINS;
    for (int i = threadIdx.x; i < BINS; i += 256) pb[i] = bins[i];
}

// Fallback (small d_ws): original global-atomic flush path.
__global__ __launch_bounds__(256) void epp_compress_atomic(
    const int* __restrict__ inst, const float* __restrict__ src,
    float* __restrict__ comp)
{
    __shared__ float bins[BINS];
    const int b = blockIdx.y;
    for (int i = threadIdx.x; i < BINS; i += 256) bins[i] = 0.0f;
    __syncthreads();
    const int total4 = ELEMS / 4;
    const int* __restrict__ instb = inst + b * HW;
    const float4* __restrict__ srcb = (const float4*)(src + (size_t)b * ELEMS);
    const int stride = gridDim.x * 256;
    for (int e4 = blockIdx.x * 256 + threadIdx.x; e4 < total4; e4 += stride) {
        float4 v = srcb[e4];
        const int e = e4 * 4;
        float vals[4] = {v.x, v.y, v.z, v.w};
#pragma unroll
        for (int k = 0; k < 4; ++k) {
            int ee = e + k, pix = ee / 9, j = ee - pix * 9;
            atomicAdd(&bins[instb[pix] * 9 + j], vals[k] * 1.1f);
        }
    }
    __syncthreads();
    float* __restrict__ compb = comp + b * BINS;
    for (int i = threadIdx.x; i < BINS; i += 256) atomicAdd(&compb[i], bins[i]);
}

// ---------------------------------------------------------------------------
// Reduce: comp[b][i] = sum over nxblk partials. 14400 outputs; coalesced
// (lane-consecutive i for fixed partial g); 4-way independent accumulators.
// ---------------------------------------------------------------------------
__global__ __launch_bounds__(256) void epp_reduce(
    const float* __restrict__ part, float* __restrict__ comp, int nxblk)
{
    int o = blockIdx.x * 256 + threadIdx.x;
    if (o >= BATCH * BINS) return;
    int b = o / BINS, i = o - b * BINS;
    const float* __restrict__ pb = part + ((size_t)b * nxblk) * BINS + i;
    float s0 = 0.f, s1 = 0.f, s2 = 0.f, s3 = 0.f;
    int g = 0;
    for (; g + 4 <= nxblk; g += 4) {
        s0 += pb[(size_t)(g + 0) * BINS];
        s1 += pb[(size_t)(g + 1) * BINS];
        s2 += pb[(size_t)(g + 2) * BINS];
        s3 += pb[(size_t)(g + 3) * BINS];
    }
    for (; g < nxblk; ++g) s0 += pb[(size_t)g * BINS];
    comp[o] = (s0 + s1) + (s2 + s3);
}

// ---------------------------------------------------------------------------
// Inflate: stage per-batch table in LDS, gather, coalesced float4 stores.
// ---------------------------------------------------------------------------
__global__ __launch_bounds__(256) void epp_inflate(
    const int* __restrict__ inst, const float* __restrict__ comp,
    float* __restrict__ out)
{
    __shared__ float bins[BINS];
    const int b = blockIdx.y;
    const float* __restrict__ compb = comp + b * BINS;
    for (int i = threadIdx.x; i < BINS; i += 256) bins[i] = compb[i];
    __syncthreads();

    const int total4 = ELEMS / 4;
    const int* __restrict__ instb = inst + b * HW;
    float4* __restrict__ outb = (float4*)(out + (size_t)b * ELEMS);
    const int stride = gridDim.x * 256;

    for (int e4 = blockIdx.x * 256 + threadIdx.x; e4 < total4; e4 += stride) {
        const int e = e4 * 4;
        float vals[4];
#pragma unroll
        for (int k = 0; k < 4; ++k) {
            int ee = e + k, pix = ee / 9, j = ee - pix * 9;
            vals[k] = bins[instb[pix] * 9 + j];
        }
        outb[e4] = make_float4(vals[0], vals[1], vals[2], vals[3]);
    }
}

extern "C" void kernel_launch(void* const* d_in, const int* in_sizes, int n_in,
                              void* d_out, int out_size, void* d_ws, size_t ws_size,
                              hipStream_t stream) {
    const int*   inst = (const int*)d_in[0];    // [B,1,H,W] int32
    const float* src  = (const float*)d_in[1];  // [B,H,W,3,3] f32
    float* out = (float*)d_out;                 // [B,H,W,3,3] f32

    const size_t compBytes = (size_t)BATCH * BINS * sizeof(float);   // 57.6 KB

    // Pick the widest partials layout that fits d_ws: [B*nxblk][BINS] + comp.
    int nxblk = 0;
    for (int cand : {256, 128, 64}) {
        size_t need = (size_t)BATCH * cand * BINS * sizeof(float) + compBytes;
        if (ws_size >= need) { nxblk = cand; break; }
    }

    if (nxblk > 0) {
        float* part = (float*)d_ws;
        float* comp = part + (size_t)BATCH * nxblk * BINS;

        dim3 cgrid(nxblk, BATCH);
        epp_compress<<<cgrid, 256, 0, stream>>>(inst, src, part, nxblk);

        int rblocks = (BATCH * BINS + 255) / 256;   // 57
        epp_reduce<<<rblocks, 256, 0, stream>>>(part, comp, nxblk);

        dim3 igrid(512, BATCH);                     // 4096 blocks, 16/CU
        epp_inflate<<<igrid, 256, 0, stream>>>(inst, comp, out);
    } else {
        // Tiny-ws fallback: original atomic path.
        float* comp = (float*)d_ws;
        hipMemsetAsync(comp, 0, compBytes, stream);
        dim3 cgrid(128, BATCH);
        epp_compress_atomic<<<cgrid, 256, 0, stream>>>(inst, src, comp);
        dim3 igrid(512, BATCH);
        epp_inflate<<<igrid, 256, 0, stream>>>(inst, comp, out);
    }
}

// Round 3
// 68.715 us; speedup vs baseline: 2.5508x; 2.5508x over previous
//
#include <hip/hip_runtime.h>

// Problem constants: B=8, H=320, W=1024, CH=CW=3, MAXINS=200
#define BATCH   8
#define HW      (320 * 1024)        // 327680 pixels per batch
#define ELEMS   (HW * 9)            // 2949120 floats per batch
#define MAXINS  200
#define BINS    (MAXINS * 9)        // 1800 bins per batch
#define SCALE      2097152.0f       // 2^21 fixed-point scale
#define INV_SCALE  (1.1f / 2097152.0f)  // fold reference's 1.1 into the unscale

// ---------------------------------------------------------------------------
// Compress: per-block LDS histogram in FIXED-POINT INT32 (ds_add_u32 is
// native; float atomicAdd on LDS was the ~3.5 cyc/lane serialization wall).
// Partials stored to d_ws as int32; no global atomics.
// ---------------------------------------------------------------------------
__global__ __launch_bounds__(256) void epp_compress(
    const int* __restrict__ inst, const float* __restrict__ src,
    int* __restrict__ part, int nxblk)
{
    __shared__ int bins[BINS];
    const int b = blockIdx.y;

    for (int i = threadIdx.x; i < BINS; i += 256) bins[i] = 0;
    __syncthreads();

    const int total4 = ELEMS / 4;                      // 737280 float4/batch
    const int* __restrict__ instb = inst + b * HW;
    const float4* __restrict__ srcb = (const float4*)(src + (size_t)b * ELEMS);
    const int stride = nxblk * 256;

    for (int e4 = blockIdx.x * 256 + threadIdx.x; e4 < total4; e4 += stride) {
        float4 v = srcb[e4];
        const int e = e4 * 4;
        float vals[4] = {v.x, v.y, v.z, v.w};
#pragma unroll
        for (int k = 0; k < 4; ++k) {
            int ee  = e + k;
            int pix = ee / 9;                          // magic-mul division
            int j   = ee - pix * 9;
            int q   = __float2int_rn(vals[k] * SCALE); // fixed-point quantize
            atomicAdd(&bins[instb[pix] * 9 + j], q);   // ds_add_u32 (native)
        }
    }
    __syncthreads();

    int* __restrict__ pb = part + ((size_t)b * nxblk + blockIdx.x) * BINS;
    for (int i = threadIdx.x; i < BINS; i += 256) pb[i] = bins[i];
}

// Fallback (tiny d_ws): float path with global-atomic flush (passed in R1).
__global__ __launch_bounds__(256) void epp_compress_atomic(
    const int* __restrict__ inst, const float* __restrict__ src,
    float* __restrict__ comp)
{
    __shared__ float bins[BINS];
    const int b = blockIdx.y;
    for (int i = threadIdx.x; i < BINS; i += 256) bins[i] = 0.0f;
    __syncthreads();
    const int total4 = ELEMS / 4;
    const int* __restrict__ instb = inst + b * HW;
    const float4* __restrict__ srcb = (const float4*)(src + (size_t)b * ELEMS);
    const int stride = gridDim.x * 256;
    for (int e4 = blockIdx.x * 256 + threadIdx.x; e4 < total4; e4 += stride) {
        float4 v = srcb[e4];
        const int e = e4 * 4;
        float vals[4] = {v.x, v.y, v.z, v.w};
#pragma unroll
        for (int k = 0; k < 4; ++k) {
            int ee = e + k, pix = ee / 9, j = ee - pix * 9;
            atomicAdd(&bins[instb[pix] * 9 + j], vals[k] * 1.1f);
        }
    }
    __syncthreads();
    float* __restrict__ compb = comp + b * BINS;
    for (int i = threadIdx.x; i < BINS; i += 256) atomicAdd(&compb[i], bins[i]);
}

// ---------------------------------------------------------------------------
// Reduce: comp[b][i] = 1.1 * (sum of int partials) / SCALE. int64 accum is
// exact; one float conversion at the end.
// ---------------------------------------------------------------------------
__global__ __launch_bounds__(256) void epp_reduce(
    const int* __restrict__ part, float* __restrict__ comp, int nxblk)
{
    int o = blockIdx.x * 256 + threadIdx.x;
    if (o >= BATCH * BINS) return;
    int b = o / BINS, i = o - b * BINS;
    const int* __restrict__ pb = part + (size_t)b * nxblk * BINS + i;
    long long s0 = 0, s1 = 0, s2 = 0, s3 = 0;
    int g = 0;
    for (; g + 4 <= nxblk; g += 4) {
        s0 += pb[(size_t)(g + 0) * BINS];
        s1 += pb[(size_t)(g + 1) * BINS];
        s2 += pb[(size_t)(g + 2) * BINS];
        s3 += pb[(size_t)(g + 3) * BINS];
    }
    for (; g < nxblk; ++g) s0 += pb[(size_t)g * BINS];
    long long s = (s0 + s1) + (s2 + s3);
    comp[o] = (float)((double)s * (double)INV_SCALE);
}

// ---------------------------------------------------------------------------
// Inflate: stage per-batch table in LDS, gather, coalesced float4 stores.
// ---------------------------------------------------------------------------
__global__ __launch_bounds__(256) void epp_inflate(
    const int* __restrict__ inst, const float* __restrict__ comp,
    float* __restrict__ out)
{
    __shared__ float bins[BINS];
    const int b = blockIdx.y;
    const float* __restrict__ compb = comp + b * BINS;
    for (int i = threadIdx.x; i < BINS; i += 256) bins[i] = compb[i];
    __syncthreads();

    const int total4 = ELEMS / 4;
    const int* __restrict__ instb = inst + b * HW;
    float4* __restrict__ outb = (float4*)(out + (size_t)b * ELEMS);
    const int stride = gridDim.x * 256;

    for (int e4 = blockIdx.x * 256 + threadIdx.x; e4 < total4; e4 += stride) {
        const int e = e4 * 4;
        float vals[4];
#pragma unroll
        for (int k = 0; k < 4; ++k) {
            int ee = e + k, pix = ee / 9, j = ee - pix * 9;
            vals[k] = bins[instb[pix] * 9 + j];
        }
        outb[e4] = make_float4(vals[0], vals[1], vals[2], vals[3]);
    }
}

extern "C" void kernel_launch(void* const* d_in, const int* in_sizes, int n_in,
                              void* d_out, int out_size, void* d_ws, size_t ws_size,
                              hipStream_t stream) {
    const int*   inst = (const int*)d_in[0];    // [B,1,H,W] int32
    const float* src  = (const float*)d_in[1];  // [B,H,W,3,3] f32
    float* out = (float*)d_out;                 // [B,H,W,3,3] f32

    const size_t compBytes = (size_t)BATCH * BINS * sizeof(float);   // 57.6 KB

    int nxblk = 0;
    for (int cand : {256, 128, 64}) {
        size_t need = (size_t)BATCH * cand * BINS * sizeof(int) + compBytes;
        if (ws_size >= need) { nxblk = cand; break; }
    }

    if (nxblk > 0) {
        int*   part = (int*)d_ws;
        float* comp = (float*)(part + (size_t)BATCH * nxblk * BINS);

        dim3 cgrid(nxblk, BATCH);
        epp_compress<<<cgrid, 256, 0, stream>>>(inst, src, part, nxblk);

        int rblocks = (BATCH * BINS + 255) / 256;   // 57
        epp_reduce<<<rblocks, 256, 0, stream>>>(part, comp, nxblk);

        dim3 igrid(512, BATCH);
        epp_inflate<<<igrid, 256, 0, stream>>>(inst, comp, out);
    } else {
        float* comp = (float*)d_ws;
        hipMemsetAsync(comp, 0, compBytes, stream);
        dim3 cgrid(128, BATCH);
        epp_compress_atomic<<<cgrid, 256, 0, stream>>>(inst, src, comp);
        dim3 igrid(512, BATCH);
        epp_inflate<<<igrid, 256, 0, stream>>>(inst, comp, out);
    }
}